// Round 1
// baseline (449.847 us; speedup 1.0000x reference)
//
#include <hip/hip_runtime.h>
#include <math.h>

#define TPB 512
#define BPB 32

// ---- LDS float offsets ----
#define OFF_X    0        // [32][136]  x, later attended  (row stride 8 per n, b-stride 136)
#define OFF_XR   4352     // [32][136]  normalized xr
#define OFF_Z    8704     // [32][360]  z chunk (8 n x 44+pad); reused as h [32][264]
#define OFF_WR   20224    // [n][m][4]
#define OFF_WL   21248    // [n][m][4]
#define OFF_WGP  22272    // [n][m][20]
#define OFF_WU   27392    // [n][m2][4]
#define OFF_WD   31488    // [m2][m][4]
#define OFF_AN   35584    // a_norm [16][4]
#define OFF_BLF  35648    // b_left [16]
#define OFF_BU   35664    // b_up [64]
#define OFF_AA   35728    // a_act [64][4]
#define OFF_BA   35984    // b_act [64][4]
#define OFF_BD   36240    // b_down [16]
#define SMEM_FLOATS 36256
#define SMEM_BYTES  (SMEM_FLOATS * 4)

// ---- Cl(3,0) pair tables (blade order 1,e1,e2,e3,e12,e13,e23,e123) ----
// 64 products x[i]*xr[k] -> 44 (path,j) slots with sign
constexpr int ZI[64] = {
    0,0,0,0,0,0,0,0,  1,1,1,1,1,1,1,1,  2,2,2,2,2,2,2,2,  4,4,4,4,4,4,4,4,
    3,3,3,3,3,3,3,3,  5,5,5,5,5,5,5,5,  6,6,6,6,6,6,6,6,  7,7,7,7,7,7,7,7};
constexpr int ZK[64] = {
    0,1,2,4,3,5,6,7,  0,1,2,4,3,5,6,7,  0,1,2,4,3,5,6,7,  0,1,2,4,3,5,6,7,
    0,1,2,4,3,5,6,7,  0,1,2,4,3,5,6,7,  0,1,2,4,3,5,6,7,  0,1,2,4,3,5,6,7};
constexpr int ZS[64] = {
    0,1,2,4,3,5,6,7,
    9,8,15,13,16,14,21,20,
    10,15,8,12,17,21,14,19,
    29,24,23,22,35,34,33,28,
    11,16,17,21,8,12,13,18,
    30,25,35,34,23,22,32,27,
    31,35,25,33,24,32,22,26,
    43,42,41,39,40,38,37,36};
constexpr int ZG[64] = {   // 1 = +, 0 = -
    1,1,1,1,1,1,1,1,
    1,1,1,1,1,1,1,1,
    1,0,1,0,1,0,1,0,
    1,0,1,0,1,0,1,0,
    1,0,0,1,1,0,0,1,
    1,0,0,1,1,0,0,1,
    1,1,0,0,1,1,0,0,
    1,1,0,0,1,1,0,0};
// slot -> path index (into w_gp[...,20]) and output blade j
constexpr int CP[44] = {
    0, 1,1,1, 2,2,2, 3,
    4, 5,5,5, 6,6,6, 7,7,7, 8,8,8, 9,
    10, 11,11,11, 12,12,12, 13,13,13, 14,14,14, 15,
    16, 17,17,17, 18,18,18, 19};
constexpr int CJ[44] = {
    0, 1,2,3, 4,5,6, 7,
    0, 1,2,3, 1,2,3, 4,5,6, 4,5,6, 7,
    0, 1,2,3, 1,2,3, 4,5,6, 4,5,6, 7,
    0, 1,2,3, 4,5,6, 7};

__device__ __forceinline__ float sigmoidf_(float v) {
    return __builtin_amdgcn_rcpf(1.0f + __expf(-v));
}

__global__ __launch_bounds__(TPB, 2)
void mv_block_kernel(const float* __restrict__ xg,
                     const float* __restrict__ w_right,
                     const float* __restrict__ a_norm,
                     const float* __restrict__ w_gp,
                     const float* __restrict__ w_left,
                     const float* __restrict__ b_left,
                     const float* __restrict__ w_up,
                     const float* __restrict__ b_up,
                     const float* __restrict__ a_act,
                     const float* __restrict__ b_act,
                     const float* __restrict__ w_down,
                     const float* __restrict__ b_down,
                     float* __restrict__ outg,
                     int ngroups)
{
    extern __shared__ float sm[];
    const int t = threadIdx.x;

    // ---------- stage weights once per block (transposed for conflict-free reads) ----------
    if (t < 256) {
        const float4 a = ((const float4*)w_right)[t];
        const float4 b = ((const float4*)w_left)[t];
        const int m = t >> 4, n = t & 15;
        *(float4*)&sm[OFF_WR + (n*16+m)*4] = a;
        *(float4*)&sm[OFF_WL + (n*16+m)*4] = b;
        sm[OFF_AA + t] = a_act[t];
        sm[OFF_BA + t] = b_act[t];
    }
    for (int f = t; f < 1280; f += TPB) {       // w_gp: [m][n][20] -> [n][m][20]
        const float4 v = ((const float4*)w_gp)[f];
        const int pair = f / 5, q = f - pair*5;
        const int m = pair >> 4, n = pair & 15;
        *(float4*)&sm[OFF_WGP + (n*16+m)*20 + q*4] = v;
    }
    for (int f = t; f < 1024; f += TPB) {       // w_up: [m2][n][4] -> [n][m2][4]; w_down: [m][m2][4] -> [m2][m][4]
        const float4 v = ((const float4*)w_up)[f];
        const int m2 = f >> 4, n = f & 15;
        *(float4*)&sm[OFF_WU + (n*64+m2)*4] = v;
        const float4 u = ((const float4*)w_down)[f];
        const int mm = f >> 6, k2 = f & 63;
        *(float4*)&sm[OFF_WD + (k2*16+mm)*4] = u;
    }
    if (t < 64)               { sm[OFF_AN + t] = a_norm[t]; sm[OFF_BU + t] = b_up[t]; }
    if (t >= 64 && t < 80)    sm[OFF_BLF + (t-64)] = b_left[t-64];
    if (t >= 80 && t < 96)    sm[OFF_BD  + (t-80)] = b_down[t-80];

    const int bl = t >> 4;   // local batch element 0..31
    const int m  = t & 15;   // output channel 0..15

    for (int g = blockIdx.x; g < ngroups; g += gridDim.x) {
        __syncthreads();     // guard LDS reuse across group iterations
        const int b0 = g * BPB;
        // ---------- stage x (coalesced) ----------
        {
            const float4* xs = (const float4*)xg + (size_t)b0 * 32;
            #pragma unroll
            for (int f0 = 0; f0 < 1024; f0 += TPB) {
                const int f = f0 + t;
                const float4 v = xs[f];
                const int bb = f >> 5, off = f & 31;
                *(float4*)&sm[OFF_X + bb*136 + off*4] = v;
            }
        }
        __syncthreads();

        // ---------- phase A: right-linear + left-linear ----------
        float xr[8] = {0,0,0,0,0,0,0,0};
        float lf[8] = {0,0,0,0,0,0,0,0};
        const float* sx = &sm[OFF_X + bl*136];
        #pragma unroll
        for (int n = 0; n < 16; ++n) {
            const float4 xa = *(const float4*)&sx[n*8];
            const float4 xb = *(const float4*)&sx[n*8+4];
            const float4 w  = *(const float4*)&sm[OFF_WR + (n*16+m)*4];
            xr[0] += xa.x*w.x; xr[1] += xa.y*w.y; xr[2] += xa.z*w.y; xr[3] += xa.w*w.y;
            xr[4] += xb.x*w.z; xr[5] += xb.y*w.z; xr[6] += xb.z*w.z; xr[7] += xb.w*w.w;
            const float4 v  = *(const float4*)&sm[OFF_WL + (n*16+m)*4];
            lf[0] += xa.x*v.x; lf[1] += xa.y*v.y; lf[2] += xa.z*v.y; lf[3] += xa.w*v.y;
            lf[4] += xb.x*v.z; lf[5] += xb.y*v.z; lf[6] += xb.z*v.z; lf[7] += xb.w*v.w;
        }

        // ---------- phase B: gated per-grade normalization ----------
        {
            const float q0 = xr[0]*xr[0];
            const float q1 = xr[1]*xr[1] + xr[2]*xr[2] + xr[3]*xr[3];
            const float q2 = xr[4]*xr[4] + xr[5]*xr[5] + xr[6]*xr[6];
            const float q3 = xr[7]*xr[7];
            const float4 an = *(const float4*)&sm[OFF_AN + m*4];
            const float i0 = __builtin_amdgcn_rcpf(sigmoidf_(an.x)*(sqrtf(q0)-1.0f)+1.0f + 1e-6f);
            const float i1 = __builtin_amdgcn_rcpf(sigmoidf_(an.y)*(sqrtf(q1)-1.0f)+1.0f + 1e-6f);
            const float i2 = __builtin_amdgcn_rcpf(sigmoidf_(an.z)*(sqrtf(q2)-1.0f)+1.0f + 1e-6f);
            const float i3 = __builtin_amdgcn_rcpf(sigmoidf_(an.w)*(sqrtf(q3)-1.0f)+1.0f + 1e-6f);
            xr[0]*=i0; xr[1]*=i1; xr[2]*=i1; xr[3]*=i1;
            xr[4]*=i2; xr[5]*=i2; xr[6]*=i2; xr[7]*=i3;
        }
        *(float4*)&sm[OFF_XR + bl*136 + m*8]     = make_float4(xr[0],xr[1],xr[2],xr[3]);
        *(float4*)&sm[OFF_XR + bl*136 + m*8 + 4] = make_float4(xr[4],xr[5],xr[6],xr[7]);

        // ---------- phase C: geometric product via 44-slot z factorization ----------
        float gp[8] = {0,0,0,0,0,0,0,0};
        #pragma unroll
        for (int c = 0; c < 2; ++c) {
            __syncthreads();   // xr ready / prior chunk's z reads done
            if (m < 8) {       // form z for n = c*8 + m
                const int n = c*8 + m;
                const float* px = &sm[OFF_X  + bl*136 + n*8];
                const float* pr = &sm[OFF_XR + bl*136 + n*8];
                float xv[8], rv[8];
                { float4 u = *(const float4*)px;     xv[0]=u.x; xv[1]=u.y; xv[2]=u.z; xv[3]=u.w; }
                { float4 u = *(const float4*)(px+4); xv[4]=u.x; xv[5]=u.y; xv[6]=u.z; xv[7]=u.w; }
                { float4 u = *(const float4*)pr;     rv[0]=u.x; rv[1]=u.y; rv[2]=u.z; rv[3]=u.w; }
                { float4 u = *(const float4*)(pr+4); rv[4]=u.x; rv[5]=u.y; rv[6]=u.z; rv[7]=u.w; }
                float z[44];
                #pragma unroll
                for (int s = 0; s < 44; ++s) z[s] = 0.0f;
                #pragma unroll
                for (int e = 0; e < 64; ++e) {
                    const float p = xv[ZI[e]] * rv[ZK[e]];
                    if (ZG[e]) z[ZS[e]] += p; else z[ZS[e]] -= p;
                }
                float* pz = &sm[OFF_Z + bl*360 + m*44];
                #pragma unroll
                for (int s = 0; s < 44; s += 4)
                    *(float4*)&pz[s] = make_float4(z[s],z[s+1],z[s+2],z[s+3]);
            }
            __syncthreads();
            #pragma unroll 2
            for (int nl = 0; nl < 8; ++nl) {
                const int n = c*8 + nl;
                const float* pz = &sm[OFF_Z + bl*360 + nl*44];
                float zr[44];
                #pragma unroll
                for (int s = 0; s < 44; s += 4) {
                    const float4 u = *(const float4*)&pz[s];
                    zr[s]=u.x; zr[s+1]=u.y; zr[s+2]=u.z; zr[s+3]=u.w;
                }
                const float* pw = &sm[OFF_WGP + (n*16+m)*20];
                float wg[20];
                #pragma unroll
                for (int s = 0; s < 20; s += 4) {
                    const float4 u = *(const float4*)&pw[s];
                    wg[s]=u.x; wg[s+1]=u.y; wg[s+2]=u.z; wg[s+3]=u.w;
                }
                #pragma unroll
                for (int s = 0; s < 44; ++s) gp[CJ[s]] += wg[CP[s]] * zr[s];
            }
        }

        // ---------- attended = (left + b_left + gp) / sqrt(2) ----------
        float att[8];
        lf[0] += sm[OFF_BLF + m];
        #pragma unroll
        for (int i = 0; i < 8; ++i) att[i] = (lf[i] + gp[i]) * 0.70710678118654752f;
        *(float4*)&sm[OFF_X + bl*136 + m*8]     = make_float4(att[0],att[1],att[2],att[3]);
        *(float4*)&sm[OFF_X + bl*136 + m*8 + 4] = make_float4(att[4],att[5],att[6],att[7]);
        __syncthreads();

        // ---------- phase D: up (64) -> silu -> down (16), in two m2-halves ----------
        float oacc[8] = {0,0,0,0,0,0,0,0};
        #pragma unroll
        for (int hf = 0; hf < 2; ++hf) {
            if (hf) __syncthreads();          // protect h region until prior down-reads done
            float h0[8] = {0,0,0,0,0,0,0,0};
            float h1[8] = {0,0,0,0,0,0,0,0};
            const int m2a = m + (hf*2)*16;
            const int m2b = m2a + 16;
            const float* sa = &sm[OFF_X + bl*136];
            #pragma unroll 4
            for (int n = 0; n < 16; ++n) {
                const float4 aa = *(const float4*)&sa[n*8];
                const float4 ab = *(const float4*)&sa[n*8+4];
                const float4 wA = *(const float4*)&sm[OFF_WU + (n*64+m2a)*4];
                const float4 wB = *(const float4*)&sm[OFF_WU + (n*64+m2b)*4];
                h0[0]+=aa.x*wA.x; h0[1]+=aa.y*wA.y; h0[2]+=aa.z*wA.y; h0[3]+=aa.w*wA.y;
                h0[4]+=ab.x*wA.z; h0[5]+=ab.y*wA.z; h0[6]+=ab.z*wA.z; h0[7]+=ab.w*wA.w;
                h1[0]+=aa.x*wB.x; h1[1]+=aa.y*wB.y; h1[2]+=aa.z*wB.y; h1[3]+=aa.w*wB.y;
                h1[4]+=ab.x*wB.z; h1[5]+=ab.y*wB.z; h1[6]+=ab.z*wB.z; h1[7]+=ab.w*wB.w;
            }
            #pragma unroll
            for (int qq = 0; qq < 2; ++qq) {
                float* hh = qq ? h1 : h0;
                const int m2 = qq ? m2b : m2a;
                hh[0] += sm[OFF_BU + m2];
                const float inv0 = hh[0];
                const float inv1 = hh[1]*hh[1] + hh[2]*hh[2] + hh[3]*hh[3];
                const float inv2 = hh[4]*hh[4] + hh[5]*hh[5] + hh[6]*hh[6];
                const float inv3 = hh[7]*hh[7];
                const float4 a4 = *(const float4*)&sm[OFF_AA + m2*4];
                const float4 b4 = *(const float4*)&sm[OFF_BA + m2*4];
                const float g0 = sigmoidf_(a4.x*inv0 + b4.x);
                const float g1 = sigmoidf_(a4.y*inv1 + b4.y);
                const float g2 = sigmoidf_(a4.z*inv2 + b4.z);
                const float g3 = sigmoidf_(a4.w*inv3 + b4.w);
                hh[0]*=g0; hh[1]*=g1; hh[2]*=g1; hh[3]*=g1;
                hh[4]*=g2; hh[5]*=g2; hh[6]*=g2; hh[7]*=g3;
                float* ph = &sm[OFF_Z + bl*264 + (m + qq*16)*8];
                *(float4*)&ph[0] = make_float4(hh[0],hh[1],hh[2],hh[3]);
                *(float4*)&ph[4] = make_float4(hh[4],hh[5],hh[6],hh[7]);
            }
            __syncthreads();
            #pragma unroll 4
            for (int mh = 0; mh < 32; ++mh) {
                const float* ph = &sm[OFF_Z + bl*264 + mh*8];
                const float4 ha = *(const float4*)&ph[0];
                const float4 hb = *(const float4*)&ph[4];
                const int m2 = hf*32 + mh;
                const float4 w = *(const float4*)&sm[OFF_WD + (m2*16+m)*4];
                oacc[0]+=ha.x*w.x; oacc[1]+=ha.y*w.y; oacc[2]+=ha.z*w.y; oacc[3]+=ha.w*w.y;
                oacc[4]+=hb.x*w.z; oacc[5]+=hb.y*w.z; oacc[6]+=hb.z*w.z; oacc[7]+=hb.w*w.w;
            }
        }

        // ---------- epilogue: out = attended + down + b_down ----------
        oacc[0] += sm[OFF_BD + m];
        float4* og = (float4*)outg + (size_t)(b0 + bl) * 32 + m*2;
        og[0] = make_float4(att[0]+oacc[0], att[1]+oacc[1], att[2]+oacc[2], att[3]+oacc[3]);
        og[1] = make_float4(att[4]+oacc[4], att[5]+oacc[5], att[6]+oacc[6], att[7]+oacc[7]);
    }
}

extern "C" void kernel_launch(void* const* d_in, const int* in_sizes, int n_in,
                              void* d_out, int out_size, void* d_ws, size_t ws_size,
                              hipStream_t stream) {
    const float* x       = (const float*)d_in[0];
    const float* w_right = (const float*)d_in[1];
    const float* a_norm  = (const float*)d_in[2];
    const float* w_gp    = (const float*)d_in[3];
    const float* w_left  = (const float*)d_in[4];
    const float* b_left  = (const float*)d_in[5];
    const float* w_up    = (const float*)d_in[6];
    const float* b_up    = (const float*)d_in[7];
    const float* a_act   = (const float*)d_in[8];
    const float* b_act   = (const float*)d_in[9];
    const float* w_down  = (const float*)d_in[10];
    const float* b_down  = (const float*)d_in[11];
    float* out = (float*)d_out;

    const int B = in_sizes[0] / 128;        // 65536
    const int ngroups = B / BPB;            // 2048

    (void)hipFuncSetAttribute((const void*)mv_block_kernel,
                              hipFuncAttributeMaxDynamicSharedMemorySize, SMEM_BYTES);
    mv_block_kernel<<<256, TPB, SMEM_BYTES, stream>>>(
        x, w_right, a_norm, w_gp, w_left, b_left,
        w_up, b_up, a_act, b_act, w_down, b_down, out, ngroups);
}